// Round 6
// baseline (380.662 us; speedup 1.0000x reference)
//
#include <hip/hip_runtime.h>
#include <hip/hip_fp16.h>
#include <cstdint>

#define CDIM 40
#define FDIM 128
#define BIN_SHIFT 8      // 256 nodes per bin
#define BIN_SZ (1 << BIN_SHIFT)

typedef _Float16 f16x8 __attribute__((ext_vector_type(8)));
typedef float f32x4 __attribute__((ext_vector_type(4)));

static __device__ __forceinline__ long long load_idx(const void* p, int is64, long long i) {
    if (is64) return ((const long long*)p)[i];
    return (long long)((const int*)p)[i];
}

static __device__ __forceinline__ unsigned packh2(float a, float b) {
    __half2 h;
    h.x = __float2half(a);
    h.y = __float2half(b);
    return *(unsigned*)&h;
}

// add 8 fp16 values (one uint4) into acc[0..8)
static __device__ __forceinline__ void addv4(float* acc, uint4 v) {
    const __half2* h = (const __half2*)&v;
    float2 f0 = __half22float2(h[0]);
    float2 f1 = __half22float2(h[1]);
    float2 f2 = __half22float2(h[2]);
    float2 f3 = __half22float2(h[3]);
    acc[0] += f0.x; acc[1] += f0.y; acc[2] += f1.x; acc[3] += f1.y;
    acc[4] += f2.x; acc[5] += f2.y; acc[6] += f3.x; acc[7] += f3.y;
}

static __device__ __forceinline__ f16x8 cvt8(float4 a, float4 b) {
    f16x8 r;
    r[0] = (_Float16)a.x; r[1] = (_Float16)a.y; r[2] = (_Float16)a.z; r[3] = (_Float16)a.w;
    r[4] = (_Float16)b.x; r[5] = (_Float16)b.y; r[6] = (_Float16)b.z; r[7] = (_Float16)b.w;
    return r;
}

// Zero per-node degree counters + zero sentinel row N of all four g tables.
__global__ __launch_bounds__(256) void k_init(int* deg, int N,
                                              __half* gA0, __half* gB0,
                                              __half* gA1, __half* gB1) {
    int i = blockIdx.x * 256 + threadIdx.x;
    if (i < N) deg[i] = 0;
    if (i < 40) {
        if (i < 16)      ((unsigned*)(gA0 + (size_t)N * 32))[i] = 0u;
        else if (i < 20) ((unsigned*)(gB0 + (size_t)N * 8))[i - 16] = 0u;
        else if (i < 36) ((unsigned*)(gA1 + (size_t)N * 32))[i - 20] = 0u;
        else             ((unsigned*)(gB1 + (size_t)N * 8))[i - 36] = 0u;
    }
}

// Count in-degrees with spread-out global atomics (100k counters, ~16 hits
// each, temporally scattered -- no hot-address serialization, unlike the
// old per-bin cursor scheme's 153k atomics on 391 addresses).
// 4 edges/thread, coalesced phases. Reads only the dst stream.
__global__ __launch_bounds__(256) void k_count(const void* ei, long long E,
                                               int* __restrict__ deg) {
    __shared__ int lflag;
    int tid = threadIdx.x;
    if (tid == 0) lflag = 1;
    __syncthreads();
    {
        const unsigned* w = (const unsigned*)ei;
        int nscan = (int)((2 * E < 4096) ? (2 * E) : 4096);
        for (int k = 1 + 2 * tid; k < nscan; k += 512)
            if (w[k] != 0u) lflag = 0;
    }
    __syncthreads();
    int is64 = lflag;
    long long base = (long long)blockIdx.x * 1024;
#pragma unroll
    for (int p = 0; p < 4; ++p) {
        long long e = base + p * 256 + tid;
        if (e < E) {
            int d = (int)load_idx(ei, is64, E + e);
            atomicAdd(&deg[d], 1);
        }
    }
}

// Per-bin scan + GEMM (391 blocks, 256 nodes each; no edge data touched).
// From deg: 4-aligned list offsets within the bin's fixed capC segment,
// degree-sorted meta {rowp, node|deg<<17}, scatter cursors, sentinel-pad
// prefill. Tail: MFMA gemm g[i,c]=fp16(dinv[i]*sum_f x[i,f]W[c,f]),
// split-store gA[node][32ch] (64B rows) + gB[node][8ch] (16B rows).
__global__ __launch_bounds__(256) void k_scanG(const int* __restrict__ deg,
                                               int capC,
                                               int2* __restrict__ meta,
                                               int* __restrict__ cursor,
                                               int* __restrict__ csr,
                                               const float* __restrict__ x,
                                               const float* __restrict__ W,
                                               __half* __restrict__ gA,
                                               __half* __restrict__ gB, int N) {
    __shared__ int lsum[4];
    __shared__ int dh[64];
    __shared__ float dinvL[BIN_SZ];
    int b = blockIdx.x, tid = threadIdx.x;
    const int wid = tid >> 6;
    const int lane = tid & 63;
    int node0 = b << BIN_SHIFT;
    int nn = min(BIN_SZ, N - node0);
    int csrBase = b * capC;

    if (tid < 64) dh[tid] = 0;
    int myc = (tid < nn) ? deg[node0 + tid] : 0;
    int psz = (myc + 3) & ~3;          // padded size (4-aligned)
    // wave-level inclusive scan of psz
    int incl = psz;
#pragma unroll
    for (int off = 1; off < 64; off <<= 1) {
        int up = __shfl_up(incl, off, 64);
        if (lane >= off) incl += up;
    }
    if (lane == 63) lsum[wid] = incl;
    dinvL[tid] = (tid < nn) ? rsqrtf(1.0f + (float)myc) : 0.0f;
    __syncthreads();
    if (tid < nn) atomicAdd(&dh[min(myc, 63)], 1);
    int woff = 0;
#pragma unroll
    for (int w = 0; w < 4; ++w) woff += (w < wid) ? lsum[w] : 0;
    int ex = woff + incl - psz;        // 4-aligned start within bin
    __syncthreads();
    // exclusive scan of the 64 degree buckets: wave 0, shfl
    if (wid == 0) {
        int dv = dh[lane];
        int di = dv;
#pragma unroll
        for (int off = 1; off < 64; off <<= 1) {
            int up = __shfl_up(di, off, 64);
            if (lane >= off) di += up;
        }
        dh[lane] = di - dv;
    }
    __syncthreads();
    // degree-sorted permuted meta (ascending degree within bin); scatter
    // cursor; sentinel pads (<=3 per node, point at zero row N)
    if (tid < nn) {
        int pos = atomicAdd(&dh[min(myc, 63)], 1);
        int2 mi;
        mi.x = csrBase + ex;
        mi.y = (node0 + tid) | (myc << 17);
        meta[node0 + pos] = mi;
        cursor[node0 + tid] = csrBase + ex;
        for (int k = myc; k < psz; ++k) csr[csrBase + ex + k] = N;
    }

    // ---- fused MFMA gemm for this bin's 256 nodes ----
    const int m = lane & 15;
    const int quad = lane >> 4;
    f16x8 bfrag[3][4];
#pragma unroll
    for (int t = 0; t < 3; ++t) {
        int c = t * 16 + m;
#pragma unroll
        for (int q = 0; q < 4; ++q) {
            if (c < CDIM) {
                const float* wp = W + (size_t)c * FDIM + q * 32 + quad * 8;
                float4 w0 = *(const float4*)wp;
                float4 w1 = *(const float4*)(wp + 4);
                bfrag[t][q] = cvt8(w0, w1);
            } else {
                f16x8 z = {0, 0, 0, 0, 0, 0, 0, 0};
                bfrag[t][q] = z;
            }
        }
    }
    __syncthreads();
#pragma unroll
    for (int i = 0; i < 4; ++i) {
        int lnode = wid * 64 + i * 16;
        int nodebase = node0 + lnode;
        if (nodebase >= N) break;
        const float* xp = x + (size_t)(nodebase + m) * FDIM + quad * 8;
        f16x8 afrag[4];
#pragma unroll
        for (int q = 0; q < 4; ++q) {
            float4 x0 = *(const float4*)(xp + q * 32);
            float4 x1 = *(const float4*)(xp + q * 32 + 4);
            afrag[q] = cvt8(x0, x1);
        }
        f32x4 acc0 = {0, 0, 0, 0}, acc1 = {0, 0, 0, 0}, acc2 = {0, 0, 0, 0};
#pragma unroll
        for (int q = 0; q < 4; ++q) {
            acc0 = __builtin_amdgcn_mfma_f32_16x16x32_f16(afrag[q], bfrag[0][q], acc0, 0, 0, 0);
            acc1 = __builtin_amdgcn_mfma_f32_16x16x32_f16(afrag[q], bfrag[1][q], acc1, 0, 0, 0);
            acc2 = __builtin_amdgcn_mfma_f32_16x16x32_f16(afrag[q], bfrag[2][q], acc2, 0, 0, 0);
        }
        float ds[4];
#pragma unroll
        for (int r = 0; r < 4; ++r) ds[r] = dinvL[lnode + quad * 4 + r];
#pragma unroll
        for (int r = 0; r < 4; ++r) {
            int node = nodebase + quad * 4 + r;
            gA[(size_t)node * 32 + m]      = __float2half(acc0[r] * ds[r]);
            gA[(size_t)node * 32 + 16 + m] = __float2half(acc1[r] * ds[r]);
            if (m < 8)
                gB[(size_t)node * 8 + m]   = __float2half(acc2[r] * ds[r]);
        }
    }
}

// Direct CSR scatter: csr[atomicAdd(&cursor[dst],1)] = src. Atomics spread
// over 100k cursors; 4B scattered writes merge via byte-masked write-back
// (per-XCD L2s flush at kernel boundary; disjoint bytes, no coherence
// traffic). Replaces the old binned-stage scatter entirely.
__global__ __launch_bounds__(256) void k_scatter(const void* ei, long long E,
                                                 int* __restrict__ cursor,
                                                 int* __restrict__ csr) {
    __shared__ int lflag;
    int tid = threadIdx.x;
    if (tid == 0) lflag = 1;
    __syncthreads();
    {
        const unsigned* w = (const unsigned*)ei;
        int nscan = (int)((2 * E < 4096) ? (2 * E) : 4096);
        for (int k = 1 + 2 * tid; k < nscan; k += 512)
            if (w[k] != 0u) lflag = 0;
    }
    __syncthreads();
    int is64 = lflag;
    long long base = (long long)blockIdx.x * 1024;
#pragma unroll
    for (int p = 0; p < 4; ++p) {
        long long e = base + p * 256 + tid;
        if (e < E) {
            int s = (int)load_idx(ei, is64, e);
            int d = (int)load_idx(ei, is64, E + e);
            int pos = atomicAdd(&cursor[d], 1);
            csr[pos] = s;
        }
    }
}

// One hop in g-space, 5 lanes per node: lane = (gidx, 8-ch chunk), 16B uint4
// per edge per lane. c<4 read gA (64B rows; 4 lanes coalesce to one line),
// c=4 reads gB (1.6MB, L2-resident). meta[gidx] (degree-sorted) packs
// {rowp, node|deg<<17}; csr read as int4 (4-aligned padded lists, pads ->
// zero sentinel row N). dinv recomputed from deg. 8-edge unroll for MLP.
// mode 0: write split fp16 tables; mode 1: fp32 out + bias.
__global__ __launch_bounds__(256) void k_gather(const int2* __restrict__ meta,
                                                const int* __restrict__ csr,
                                                const __half* __restrict__ gA,
                                                const __half* __restrict__ gB,
                                                const float* __restrict__ b,
                                                __half* __restrict__ goA,
                                                __half* __restrict__ goB,
                                                float* __restrict__ outF,
                                                int N, int mode) {
    unsigned t = blockIdx.x * 256 + threadIdx.x;
    unsigned gidx = t / 5, c = t - gidx * 5;
    if (gidx >= (unsigned)N) return;
    int2 mi = meta[gidx];
    int j = mi.x;
    int node = mi.y & 0x1FFFF;
    int deg = mi.y >> 17;
    int end_pad = j + ((deg + 3) & ~3);
    const uint4* src;
    unsigned stride;
    if (c < 4) { src = (const uint4*)gA + c; stride = 4; }
    else       { src = (const uint4*)gB;     stride = 1; }
    float acc[8] = {0, 0, 0, 0, 0, 0, 0, 0};
    addv4(acc, src[(size_t)node * stride]);
    for (; j + 8 <= end_pad; j += 8) {
        int4 c0 = *(const int4*)&csr[j];
        int4 c1 = *(const int4*)&csr[j + 4];
        uint4 v0 = src[(size_t)c0.x * stride];
        uint4 v1 = src[(size_t)c0.y * stride];
        uint4 v2 = src[(size_t)c0.z * stride];
        uint4 v3 = src[(size_t)c0.w * stride];
        uint4 v4 = src[(size_t)c1.x * stride];
        uint4 v5 = src[(size_t)c1.y * stride];
        uint4 v6 = src[(size_t)c1.z * stride];
        uint4 v7 = src[(size_t)c1.w * stride];
        addv4(acc, v0); addv4(acc, v1); addv4(acc, v2); addv4(acc, v3);
        addv4(acc, v4); addv4(acc, v5); addv4(acc, v6); addv4(acc, v7);
    }
    if (j < end_pad) {
        int4 c0 = *(const int4*)&csr[j];
        uint4 v0 = src[(size_t)c0.x * stride];
        uint4 v1 = src[(size_t)c0.y * stride];
        uint4 v2 = src[(size_t)c0.z * stride];
        uint4 v3 = src[(size_t)c0.w * stride];
        addv4(acc, v0); addv4(acc, v1); addv4(acc, v2); addv4(acc, v3);
    }
    float d = rsqrtf(1.0f + (float)deg);
    if (mode == 0) {
        float s = d * d;
        uint4 o;
        o.x = packh2(acc[0] * s, acc[1] * s);
        o.y = packh2(acc[2] * s, acc[3] * s);
        o.z = packh2(acc[4] * s, acc[5] * s);
        o.w = packh2(acc[6] * s, acc[7] * s);
        if (c < 4) ((uint4*)goA)[(size_t)node * 4 + c] = o;
        else       ((uint4*)goB)[(size_t)node] = o;
    } else {
        float4 bv0 = ((const float4*)b)[2 * c];
        float4 bv1 = ((const float4*)b)[2 * c + 1];
        float4 o0, o1;
        o0.x = acc[0] * d + bv0.x;
        o0.y = acc[1] * d + bv0.y;
        o0.z = acc[2] * d + bv0.z;
        o0.w = acc[3] * d + bv0.w;
        o1.x = acc[4] * d + bv1.x;
        o1.y = acc[5] * d + bv1.y;
        o1.z = acc[6] * d + bv1.z;
        o1.w = acc[7] * d + bv1.w;
        ((float4*)outF)[(size_t)node * 10 + 2 * c]     = o0;
        ((float4*)outF)[(size_t)node * 10 + 2 * c + 1] = o1;
    }
}

static inline size_t align256(size_t v) { return (v + 255) & ~(size_t)255; }

extern "C" void kernel_launch(void* const* d_in, const int* in_sizes, int n_in,
                              void* d_out, int out_size, void* d_ws, size_t ws_size,
                              hipStream_t stream) {
    const float* x  = (const float*)d_in[0];
    const void*  ei = d_in[1];
    const float* W  = (const float*)d_in[2];
    const float* b  = (const float*)d_in[3];
    float* out = (float*)d_out;

    const int N = in_sizes[0] / FDIM;                 // 100000
    const long long E = (long long)in_sizes[1] / 2;   // 1600000

    const int nb = (N + BIN_SZ - 1) >> BIN_SHIFT;            // 391 bins
    int capRec = (int)(E / nb) + 2048;                       // bin edge capacity (+32 sigma)
    int capC = (capRec + BIN_SZ * 3 + 1027) & ~3;            // csr capacity (4-pads)

    char* wsb = (char*)d_ws;
    size_t off = 0;
    int*      cursor  = (int*)(wsb + off);      off = align256(off + (size_t)N * 4);
    int*      deg     = (int*)(wsb + off);      off = align256(off + (size_t)N * 4);
    int2*     meta    = (int2*)(wsb + off);     off = align256(off + (size_t)N * 8);
    __half*   gA0     = (__half*)(wsb + off);   off = align256(off + (size_t)(N + 1) * 32 * 2);
    __half*   gB0     = (__half*)(wsb + off);   off = align256(off + (size_t)(N + 1) * 8 * 2);
    __half*   gA1     = (__half*)(wsb + off);   off = align256(off + (size_t)(N + 1) * 32 * 2);
    __half*   gB1     = (__half*)(wsb + off);   off = align256(off + (size_t)(N + 1) * 8 * 2);
    int*      csr     = (int*)(wsb + off);      off = align256(off + (size_t)nb * capC * 4);

    const int B = 256;
    const int nbN  = (N + 255) / 256;                        // 391
    const int nbE  = (int)((E + 1023) / 1024);               // 1563 (4 edges/thread)
    const unsigned GT = 5u * (unsigned)N;
    const int nbGA = (int)((GT + B - 1) / B);

    k_init   <<<nbN, B, 0, stream>>>(deg, N, gA0, gB0, gA1, gB1);
    k_count  <<<nbE, B, 0, stream>>>(ei, E, deg);
    k_scanG  <<<nb, B, 0, stream>>>(deg, capC, meta, cursor, csr, x, W, gA0, gB0, N);
    k_scatter<<<nbE, B, 0, stream>>>(ei, E, cursor, csr);
    k_gather <<<nbGA, B, 0, stream>>>(meta, csr, gA0, gB0, b, gA1, gB1, nullptr, N, 0);
    k_gather <<<nbGA, B, 0, stream>>>(meta, csr, gA1, gB1, b, nullptr, nullptr, out, N, 1);
}

// Round 7
// 222.890 us; speedup vs baseline: 1.7078x; 1.7078x over previous
//
#include <hip/hip_runtime.h>
#include <hip/hip_fp16.h>
#include <cstdint>

#define CDIM 40
#define FDIM 128
#define BIN_SHIFT 8      // 256 nodes per bin
#define BIN_SZ (1 << BIN_SHIFT)
#define CHUNK 2048       // edges per counting/scatter chunk
#define STAGE_CAP 8192   // LDS-staged csr ints per bin (32KB)

typedef _Float16 f16x8 __attribute__((ext_vector_type(8)));
typedef float f32x4 __attribute__((ext_vector_type(4)));

static __device__ __forceinline__ long long load_idx(const void* p, int is64, long long i) {
    if (is64) return ((const long long*)p)[i];
    return (long long)((const int*)p)[i];
}

static __device__ __forceinline__ unsigned packh2(float a, float b) {
    __half2 h;
    h.x = __float2half(a);
    h.y = __float2half(b);
    return *(unsigned*)&h;
}

// add 8 fp16 values (one uint4) into acc[0..8)
static __device__ __forceinline__ void addv4(float* acc, uint4 v) {
    const __half2* h = (const __half2*)&v;
    float2 f0 = __half22float2(h[0]);
    float2 f1 = __half22float2(h[1]);
    float2 f2 = __half22float2(h[2]);
    float2 f3 = __half22float2(h[3]);
    acc[0] += f0.x; acc[1] += f0.y; acc[2] += f1.x; acc[3] += f1.y;
    acc[4] += f2.x; acc[5] += f2.y; acc[6] += f3.x; acc[7] += f3.y;
}

static __device__ __forceinline__ f16x8 cvt8(float4 a, float4 b) {
    f16x8 r;
    r[0] = (_Float16)a.x; r[1] = (_Float16)a.y; r[2] = (_Float16)a.z; r[3] = (_Float16)a.w;
    r[4] = (_Float16)b.x; r[5] = (_Float16)b.y; r[6] = (_Float16)b.z; r[7] = (_Float16)b.w;
    return r;
}

// P1: per-(chunk,bin) counts. Reads the dst stream only; LDS counters; one
// coalesced row write per chunk. NO global atomics (the old kA3 burned a
// ~391-deep serialized atomic chain per bin cursor). Block 0 also zeroes the
// sentinel row N of the four g tables.
__global__ __launch_bounds__(256) void k_cnt(const void* ei, long long E,
                                             int nb, int* __restrict__ cnt,
                                             __half* gA0, __half* gB0,
                                             __half* gA1, __half* gB1, int N) {
    __shared__ int lcnt[512];
    __shared__ int lflag;
    int tid = threadIdx.x;
    if (blockIdx.x == 0 && tid < 40) {
        if (tid < 16)      ((unsigned*)(gA0 + (size_t)N * 32))[tid] = 0u;
        else if (tid < 20) ((unsigned*)(gB0 + (size_t)N * 8))[tid - 16] = 0u;
        else if (tid < 36) ((unsigned*)(gA1 + (size_t)N * 32))[tid - 20] = 0u;
        else               ((unsigned*)(gB1 + (size_t)N * 8))[tid - 36] = 0u;
    }
    if (tid == 0) lflag = 1;
    for (int i = tid; i < nb; i += 256) lcnt[i] = 0;
    __syncthreads();
    {
        const unsigned* w = (const unsigned*)ei;
        int nscan = (int)((2 * E < 4096) ? (2 * E) : 4096);
        for (int k = 1 + 2 * tid; k < nscan; k += 512)
            if (w[k] != 0u) lflag = 0;
    }
    __syncthreads();
    int is64 = lflag;
    long long base = (long long)blockIdx.x * CHUNK;
    int nk = (int)min((long long)CHUNK, E - base);
    for (int k = tid; k < nk; k += 256) {
        int d = (int)load_idx(ei, is64, E + base + k);
        atomicAdd(&lcnt[d >> BIN_SHIFT], 1);
    }
    __syncthreads();
    for (int i = tid; i < nb; i += 256)
        cnt[(size_t)blockIdx.x * nb + i] = lcnt[i];
}

// P2: per-bin exclusive scan of its cnt column over all chunks, in place ->
// absolute binned bases (b*capRec + prefix). binTot[b] = bin edge count.
__global__ __launch_bounds__(256) void k_scan(int* __restrict__ cnt,
                                              int* __restrict__ binTot,
                                              int nchunk, int nb, int capRec) {
    __shared__ int lsum[4];
    int b = blockIdx.x, tid = threadIdx.x;
    const int wid = tid >> 6;
    const int lane = tid & 63;
    int running = b * capRec;
    for (int c0 = 0; c0 < nchunk; c0 += 256) {
        int c = c0 + tid;
        int v = (c < nchunk) ? cnt[(size_t)c * nb + b] : 0;
        int incl = v;
#pragma unroll
        for (int off = 1; off < 64; off <<= 1) {
            int up = __shfl_up(incl, off, 64);
            if (lane >= off) incl += up;
        }
        if (lane == 63) lsum[wid] = incl;
        __syncthreads();
        int woff = 0;
#pragma unroll
        for (int w = 0; w < 4; ++w) woff += (w < wid) ? lsum[w] : 0;
        int total = lsum[0] + lsum[1] + lsum[2] + lsum[3];
        if (c < nchunk) cnt[(size_t)c * nb + b] = running + woff + incl - v;
        running += total;
        __syncthreads();
    }
    if (tid == 0) binTot[b] = running - b * capRec;
}

// P3: deterministic binning scatter. Bases are precomputed (cnt row), so no
// staging and no global atomics: LDS-atomic local offset + direct packed
// write {dlocal:8 | src:17}. Writes cluster ~5-consecutive per bin per chunk
// (merged lines), unlike R6's per-node scatter (103MB write-amp).
__global__ __launch_bounds__(256) void k_scat(const void* ei, long long E,
                                              int nb, const int* __restrict__ cnt,
                                              unsigned* __restrict__ binned) {
    __shared__ int lcnt[512];
    __shared__ int lbase[512];
    __shared__ int lflag;
    int tid = threadIdx.x;
    if (tid == 0) lflag = 1;
    for (int i = tid; i < nb; i += 256) {
        lcnt[i] = 0;
        lbase[i] = cnt[(size_t)blockIdx.x * nb + i];
    }
    __syncthreads();
    {
        const unsigned* w = (const unsigned*)ei;
        int nscan = (int)((2 * E < 4096) ? (2 * E) : 4096);
        for (int k = 1 + 2 * tid; k < nscan; k += 512)
            if (w[k] != 0u) lflag = 0;
    }
    __syncthreads();
    int is64 = lflag;
    long long base = (long long)blockIdx.x * CHUNK;
    int nk = (int)min((long long)CHUNK, E - base);
    for (int k = tid; k < nk; k += 256) {
        long long e = base + k;
        int s = (int)load_idx(ei, is64, e);
        int d = (int)load_idx(ei, is64, E + e);
        int bin = d >> BIN_SHIFT;
        int loc = atomicAdd(&lcnt[bin], 1);
        binned[lbase[bin] + loc] = (unsigned)s | ((unsigned)(d & (BIN_SZ - 1)) << 17);
    }
}

// Fused pass B + GEMM: one block per bin (256 nodes).
// Build: per-node degree, dinv (LDS), degree-sorted meta {rowp, node|deg<<17},
// CSR segment (4-aligned lists, sentinel pads -> zero row N). Wave-shfl scans.
// Tail: MFMA gemm g[i,c] = fp16(dinv[i]*sum_f x[i,f]W[c,f]) for this bin's
// nodes, split-store gA[node][32ch] (64B rows) + gB[node][8ch] (16B rows).
__global__ __launch_bounds__(256) void kBG(const unsigned* __restrict__ binned,
                                           const int* __restrict__ binTot,
                                           int capRec, int capC,
                                           int2* __restrict__ meta,
                                           int* __restrict__ cursorG,
                                           int* __restrict__ csr,
                                           const float* __restrict__ x,
                                           const float* __restrict__ W,
                                           __half* __restrict__ gA,
                                           __half* __restrict__ gB, int N) {
    __shared__ int lcnt[BIN_SZ];
    __shared__ int lsum[4];
    __shared__ int dh[64];
    __shared__ float dinvL[BIN_SZ];
    __shared__ int stage[STAGE_CAP];
    int b = blockIdx.x, tid = threadIdx.x;
    const int wid = tid >> 6;
    const int lane = tid & 63;
    int node0 = b << BIN_SHIFT;
    int nn = min(BIN_SZ, N - node0);
    int recBase = b * capRec;
    int csrBase = b * capC;
    int nedges = binTot[b];

    lcnt[tid] = 0;
    if (tid < 64) dh[tid] = 0;
    __syncthreads();
    for (int t = tid; t < nedges; t += 256)
        atomicAdd(&lcnt[(binned[recBase + t] >> 17) & (BIN_SZ - 1)], 1);
    __syncthreads();
    int myc = lcnt[tid];
    int psz = (myc + 3) & ~3;          // padded size (4-aligned)
    // wave-level inclusive scan of psz (no barriers)
    int incl = psz;
#pragma unroll
    for (int off = 1; off < 64; off <<= 1) {
        int up = __shfl_up(incl, off, 64);
        if (lane >= off) incl += up;
    }
    if (lane == 63) lsum[wid] = incl;
    if (tid < nn) {
        dinvL[tid] = rsqrtf(1.0f + (float)myc);
        atomicAdd(&dh[min(myc, 63)], 1);
    } else {
        dinvL[tid] = 0.0f;
    }
    __syncthreads();
    int woff = 0;
#pragma unroll
    for (int w = 0; w < 4; ++w) woff += (w < wid) ? lsum[w] : 0;
    int ex = woff + incl - psz;        // 4-aligned start within bin
    int total = lsum[0] + lsum[1] + lsum[2] + lsum[3];
    // exclusive scan of the 64 degree buckets: wave 0, shfl
    if (wid == 0) {
        int dv = dh[lane];
        int di = dv;
#pragma unroll
        for (int off = 1; off < 64; off <<= 1) {
            int up = __shfl_up(di, off, 64);
            if (lane >= off) di += up;
        }
        dh[lane] = di - dv;
    }
    __syncthreads();
    // degree-sorted permuted meta (ascending degree within bin)
    if (tid < nn) {
        int pos = atomicAdd(&dh[min(myc, 63)], 1);
        int2 mi;
        mi.x = csrBase + ex;
        mi.y = (node0 + tid) | (myc << 17);
        meta[node0 + pos] = mi;
    }
    __syncthreads();
    lcnt[tid] = ex;                    // scatter cursors (real-entry start)
    __syncthreads();
    if (total <= STAGE_CAP) {
        // prefill with sentinel N (covers pad slots)
        for (int t = tid; t < total; t += 256) stage[t] = N;
        __syncthreads();
        for (int t = tid; t < nedges; t += 256) {
            unsigned v = binned[recBase + t];
            int src = (int)(v & 0x1FFFFu);
            int dl  = (int)((v >> 17) & (BIN_SZ - 1));
            int p = atomicAdd(&lcnt[dl], 1);
            stage[p] = src;
        }
        __syncthreads();
        const int4* sp = (const int4*)stage;
        int4* cp = (int4*)(csr + csrBase);
        for (int t = tid; t < (total >> 2); t += 256) cp[t] = sp[t];
    } else {
        // overflow fallback (never hit for random graphs): global cursors
        if (tid < nn) cursorG[node0 + tid] = csrBase + ex;
        __syncthreads();
        for (int t = tid; t < nedges; t += 256) {
            unsigned v = binned[recBase + t];
            int src = (int)(v & 0x1FFFFu);
            int dl  = (int)((v >> 17) & (BIN_SZ - 1));
            int p = atomicAdd(&cursorG[node0 + dl], 1);
            csr[p] = src;
        }
        if (tid < nn)
            for (int k = myc; k < psz; ++k) csr[csrBase + ex + k] = N;
    }
    __syncthreads();

    // ---- fused MFMA gemm for this bin's 256 nodes ----
    const int m = lane & 15;
    const int quad = lane >> 4;
    f16x8 bfrag[3][4];
#pragma unroll
    for (int t = 0; t < 3; ++t) {
        int c = t * 16 + m;
#pragma unroll
        for (int q = 0; q < 4; ++q) {
            if (c < CDIM) {
                const float* wp = W + (size_t)c * FDIM + q * 32 + quad * 8;
                float4 w0 = *(const float4*)wp;
                float4 w1 = *(const float4*)(wp + 4);
                bfrag[t][q] = cvt8(w0, w1);
            } else {
                f16x8 z = {0, 0, 0, 0, 0, 0, 0, 0};
                bfrag[t][q] = z;
            }
        }
    }
#pragma unroll
    for (int i = 0; i < 4; ++i) {
        int lnode = wid * 64 + i * 16;
        int nodebase = node0 + lnode;
        if (nodebase >= N) break;
        const float* xp = x + (size_t)(nodebase + m) * FDIM + quad * 8;
        f16x8 afrag[4];
#pragma unroll
        for (int q = 0; q < 4; ++q) {
            float4 x0 = *(const float4*)(xp + q * 32);
            float4 x1 = *(const float4*)(xp + q * 32 + 4);
            afrag[q] = cvt8(x0, x1);
        }
        f32x4 acc0 = {0, 0, 0, 0}, acc1 = {0, 0, 0, 0}, acc2 = {0, 0, 0, 0};
#pragma unroll
        for (int q = 0; q < 4; ++q) {
            acc0 = __builtin_amdgcn_mfma_f32_16x16x32_f16(afrag[q], bfrag[0][q], acc0, 0, 0, 0);
            acc1 = __builtin_amdgcn_mfma_f32_16x16x32_f16(afrag[q], bfrag[1][q], acc1, 0, 0, 0);
            acc2 = __builtin_amdgcn_mfma_f32_16x16x32_f16(afrag[q], bfrag[2][q], acc2, 0, 0, 0);
        }
        float ds[4];
#pragma unroll
        for (int r = 0; r < 4; ++r) ds[r] = dinvL[lnode + quad * 4 + r];
#pragma unroll
        for (int r = 0; r < 4; ++r) {
            int node = nodebase + quad * 4 + r;
            gA[(size_t)node * 32 + m]      = __float2half(acc0[r] * ds[r]);
            gA[(size_t)node * 32 + 16 + m] = __float2half(acc1[r] * ds[r]);
            if (m < 8)
                gB[(size_t)node * 8 + m]   = __float2half(acc2[r] * ds[r]);
        }
    }
}

// One hop in g-space, 5 lanes per node: lane = (gidx, 8-ch chunk), 16B uint4
// per edge per lane. c<4 read gA (64B rows; 4 lanes coalesce to one line),
// c=4 reads gB (1.6MB, L2-resident). meta[gidx] (degree-sorted) packs
// {rowp, node|deg<<17}; csr read as int4 (4-aligned padded lists, pads ->
// zero sentinel row N). dinv recomputed from deg. 8-edge unroll for MLP.
// mode 0: write split fp16 tables; mode 1: fp32 out + bias.
__global__ __launch_bounds__(256) void k_gather(const int2* __restrict__ meta,
                                                const int* __restrict__ csr,
                                                const __half* __restrict__ gA,
                                                const __half* __restrict__ gB,
                                                const float* __restrict__ b,
                                                __half* __restrict__ goA,
                                                __half* __restrict__ goB,
                                                float* __restrict__ outF,
                                                int N, int mode) {
    unsigned t = blockIdx.x * 256 + threadIdx.x;
    unsigned gidx = t / 5, c = t - gidx * 5;
    if (gidx >= (unsigned)N) return;
    int2 mi = meta[gidx];
    int j = mi.x;
    int node = mi.y & 0x1FFFF;
    int deg = mi.y >> 17;
    int end_pad = j + ((deg + 3) & ~3);
    const uint4* src;
    unsigned stride;
    if (c < 4) { src = (const uint4*)gA + c; stride = 4; }
    else       { src = (const uint4*)gB;     stride = 1; }
    float acc[8] = {0, 0, 0, 0, 0, 0, 0, 0};
    addv4(acc, src[(size_t)node * stride]);
    for (; j + 8 <= end_pad; j += 8) {
        int4 c0 = *(const int4*)&csr[j];
        int4 c1 = *(const int4*)&csr[j + 4];
        uint4 v0 = src[(size_t)c0.x * stride];
        uint4 v1 = src[(size_t)c0.y * stride];
        uint4 v2 = src[(size_t)c0.z * stride];
        uint4 v3 = src[(size_t)c0.w * stride];
        uint4 v4 = src[(size_t)c1.x * stride];
        uint4 v5 = src[(size_t)c1.y * stride];
        uint4 v6 = src[(size_t)c1.z * stride];
        uint4 v7 = src[(size_t)c1.w * stride];
        addv4(acc, v0); addv4(acc, v1); addv4(acc, v2); addv4(acc, v3);
        addv4(acc, v4); addv4(acc, v5); addv4(acc, v6); addv4(acc, v7);
    }
    if (j < end_pad) {
        int4 c0 = *(const int4*)&csr[j];
        uint4 v0 = src[(size_t)c0.x * stride];
        uint4 v1 = src[(size_t)c0.y * stride];
        uint4 v2 = src[(size_t)c0.z * stride];
        uint4 v3 = src[(size_t)c0.w * stride];
        addv4(acc, v0); addv4(acc, v1); addv4(acc, v2); addv4(acc, v3);
    }
    float d = rsqrtf(1.0f + (float)deg);
    if (mode == 0) {
        float s = d * d;
        uint4 o;
        o.x = packh2(acc[0] * s, acc[1] * s);
        o.y = packh2(acc[2] * s, acc[3] * s);
        o.z = packh2(acc[4] * s, acc[5] * s);
        o.w = packh2(acc[6] * s, acc[7] * s);
        if (c < 4) ((uint4*)goA)[(size_t)node * 4 + c] = o;
        else       ((uint4*)goB)[(size_t)node] = o;
    } else {
        float4 bv0 = ((const float4*)b)[2 * c];
        float4 bv1 = ((const float4*)b)[2 * c + 1];
        float4 o0, o1;
        o0.x = acc[0] * d + bv0.x;
        o0.y = acc[1] * d + bv0.y;
        o0.z = acc[2] * d + bv0.z;
        o0.w = acc[3] * d + bv0.w;
        o1.x = acc[4] * d + bv1.x;
        o1.y = acc[5] * d + bv1.y;
        o1.z = acc[6] * d + bv1.z;
        o1.w = acc[7] * d + bv1.w;
        ((float4*)outF)[(size_t)node * 10 + 2 * c]     = o0;
        ((float4*)outF)[(size_t)node * 10 + 2 * c + 1] = o1;
    }
}

static inline size_t align256(size_t v) { return (v + 255) & ~(size_t)255; }

extern "C" void kernel_launch(void* const* d_in, const int* in_sizes, int n_in,
                              void* d_out, int out_size, void* d_ws, size_t ws_size,
                              hipStream_t stream) {
    const float* x  = (const float*)d_in[0];
    const void*  ei = d_in[1];
    const float* W  = (const float*)d_in[2];
    const float* b  = (const float*)d_in[3];
    float* out = (float*)d_out;

    const int N = in_sizes[0] / FDIM;                 // 100000
    const long long E = (long long)in_sizes[1] / 2;   // 1600000

    const int nb     = (N + BIN_SZ - 1) >> BIN_SHIFT;        // 391 bins
    const int nchunk = (int)((E + CHUNK - 1) / CHUNK);       // 782 chunks
    int capRec = (int)(E / nb) + 2048;                       // bin edge capacity
    if (capRec > STAGE_CAP) capRec = STAGE_CAP;
    int capC = (capRec + BIN_SZ * 3 + 1027) & ~3;            // csr capacity (4-pads)

    char* wsb = (char*)d_ws;
    size_t off = 0;
    int*      cnt     = (int*)(wsb + off);      off = align256(off + (size_t)nchunk * nb * 4);
    int*      binTot  = (int*)(wsb + off);      off = align256(off + (size_t)nb * 4);
    int*      cursorG = (int*)(wsb + off);      off = align256(off + (size_t)N * 4);
    int2*     meta    = (int2*)(wsb + off);     off = align256(off + (size_t)N * 8);
    __half*   gA0     = (__half*)(wsb + off);   off = align256(off + (size_t)(N + 1) * 32 * 2);
    __half*   gB0     = (__half*)(wsb + off);   off = align256(off + (size_t)(N + 1) * 8 * 2);
    __half*   gA1     = (__half*)(wsb + off);   off = align256(off + (size_t)(N + 1) * 32 * 2);
    __half*   gB1     = (__half*)(wsb + off);   off = align256(off + (size_t)(N + 1) * 8 * 2);
    unsigned* binned  = (unsigned*)(wsb + off); off = align256(off + (size_t)nb * capRec * 4);
    int*      csr     = (int*)(wsb + off);      off = align256(off + (size_t)nb * capC * 4);

    const int B = 256;
    const unsigned GT = 5u * (unsigned)N;
    const int nbGA = (int)((GT + B - 1) / B);

    k_cnt   <<<nchunk, B, 0, stream>>>(ei, E, nb, cnt, gA0, gB0, gA1, gB1, N);
    k_scan  <<<nb, B, 0, stream>>>(cnt, binTot, nchunk, nb, capRec);
    k_scat  <<<nchunk, B, 0, stream>>>(ei, E, nb, cnt, binned);
    kBG     <<<nb, B, 0, stream>>>(binned, binTot, capRec, capC, meta, cursorG, csr,
                                   x, W, gA0, gB0, N);
    k_gather<<<nbGA, B, 0, stream>>>(meta, csr, gA0, gB0, b, gA1, gB1, nullptr, N, 0);
    k_gather<<<nbGA, B, 0, stream>>>(meta, csr, gA1, gB1, b, nullptr, nullptr, out, N, 1);
}